// Round 9
// baseline (47.692 us; speedup 1.0000x reference)
//
#include <hip/hip_runtime.h>

#define GRIDN 64
#define NVOX (GRIDN * GRIDN * GRIDN)
#define VOXF (1.0f / 64.0f)
#define QCUT 20.0f               // exp(-10) truncation; bound 4096*e^-10=0.186 < 0.24
#define EXPSCL (-0.72134752044f) // -0.5 * log2(e); folded into table coefficients
#define SKIPTH (QCUT * EXPSCL)   // q' < this  <=>  q > QCUT

// Workspace layout (floats):
//  cullA[N]  float4: (mux, muy, muz, rx)       -- dense 32B cull stream
//  cullB[N]  float4: (ry, rz, 0, 0)
//  rec[N]    3x float4 (48B): a0=(A',B',C',2D'), a1=(2E',2F',.25/A',dens), a2=(mu,pad)
//  part[4*NVOX]  quarter partial volumes
#define WS_CULLA 0
#define WS_CULLB (4 * 4096)
#define WS_REC   (8 * 4096)
#define WS_PART  (20 * 4096)

__global__ __launch_bounds__(256) void prep_kernel(
    const float* __restrict__ means, const float* __restrict__ dens,
    const float* __restrict__ scales, const float* __restrict__ rots,
    float* __restrict__ ws, float* __restrict__ radii_out, int N)
{
    int i = blockIdx.x * 256 + threadIdx.x;
    if (i >= N) return;

    float qw = rots[i * 4 + 0], qx = rots[i * 4 + 1];
    float qy = rots[i * 4 + 2], qz = rots[i * 4 + 3];
    float inm = rsqrtf(qw * qw + qx * qx + qy * qy + qz * qz);
    qw *= inm; qx *= inm; qy *= inm; qz *= inm;
    float r00 = 1.f - 2.f * (qy * qy + qz * qz);
    float r01 = 2.f * (qx * qy - qw * qz);
    float r02 = 2.f * (qx * qz + qw * qy);
    float r10 = 2.f * (qx * qy + qw * qz);
    float r11 = 1.f - 2.f * (qx * qx + qz * qz);
    float r12 = 2.f * (qy * qz - qw * qx);
    float r20 = 2.f * (qx * qz - qw * qy);
    float r21 = 2.f * (qy * qz + qw * qx);
    float r22 = 1.f - 2.f * (qx * qx + qy * qy);

    float s0 = scales[i * 3 + 0], s1 = scales[i * 3 + 1], s2 = scales[i * 3 + 2];
    float v0 = s0 * s0, v1 = s1 * s1, v2 = s2 * s2;
    float i0 = 1.f / v0, i1 = 1.f / v1, i2 = 1.f / v2;

    // Sinv = R diag(1/s^2) R^T, scaled by EXPSCL
    float A = (r00 * r00 * i0 + r01 * r01 * i1 + r02 * r02 * i2) * EXPSCL;
    float B = (r10 * r10 * i0 + r11 * r11 * i1 + r12 * r12 * i2) * EXPSCL;
    float C = (r20 * r20 * i0 + r21 * r21 * i1 + r22 * r22 * i2) * EXPSCL;
    float D = (r00 * r10 * i0 + r01 * r11 * i1 + r02 * r12 * i2) * EXPSCL;
    float E = (r00 * r20 * i0 + r01 * r21 * i1 + r02 * r22 * i2) * EXPSCL;
    float F = (r10 * r20 * i0 + r11 * r21 * i1 + r12 * r22 * i2) * EXPSCL;

    // Covariance diagonal -> exact AABB half-widths of {q<=QCUT}
    float Cxx = r00 * r00 * v0 + r01 * r01 * v1 + r02 * r02 * v2;
    float Cyy = r10 * r10 * v0 + r11 * r11 * v1 + r12 * r12 * v2;
    float Czz = r20 * r20 * v0 + r21 * r21 * v1 + r22 * r22 * v2;

    float mx = means[i * 3 + 0], my = means[i * 3 + 1], mz = means[i * 3 + 2];
    float rx = sqrtf(QCUT * Cxx), ry = sqrtf(QCUT * Cyy), rz = sqrtf(QCUT * Czz);

    float4 ca; ca.x = mx; ca.y = my; ca.z = mz; ca.w = rx;
    float4 cb; cb.x = ry; cb.y = rz; cb.z = 0.f; cb.w = 0.f;
    ((float4*)(ws + WS_CULLA))[i] = ca;
    ((float4*)(ws + WS_CULLB))[i] = cb;

    float4* R = (float4*)(ws + WS_REC + (size_t)i * 12);
    float4 w0; w0.x = A; w0.y = B; w0.z = C; w0.w = 2.f * D;
    float4 w1; w1.x = 2.f * E; w1.y = 2.f * F; w1.z = 0.25f / A; w1.w = dens[i];
    float4 w2; w2.x = mx; w2.y = my; w2.z = mz; w2.w = 0.f;
    R[0] = w0; R[1] = w1; R[2] = w2;

    float m = fmaxf(s0, fmaxf(s1, s2));
    radii_out[i] = ceilf(m * 3.0f * 64.0f);
}

// 4096 blocks x 256 threads (4 waves). Tile = 8x8x4 voxels (VPT=4 along x);
// tile covered by 4 blocks (quarters of the gaussian chunks).
// Phase 1: each wave culls its 4 chunks, compacting survivor indices into a
//          per-wave LDS segment (ballot-prefix, stable order).
// Phase 2: waves take equal slices of the concatenated list (deterministic
//          boundaries from counts) and run the s_load-pipelined math loop.
__global__ __launch_bounds__(256) void vox_kernel(
    const float* __restrict__ ws, float* __restrict__ part, int N)
{
    __shared__ int slist[4][256];
    __shared__ int lenw[4];
    __shared__ float4 plds[4][64];

    const float* rec = ws + WS_REC;
    const int tid = threadIdx.x;
    const int lane = tid & 63, wave = tid >> 6;
    // bijective scramble (gcd(1657,4096)=1): spread heavy regions across CUs
    const int bs = (blockIdx.x * 1657) & 4095;
    const int tile = bs >> 2, q = bs & 3;
    const int tX = tile & 7, tY = (tile >> 3) & 7, tZ = tile >> 6;  // 8 x 8 x 16 tiles
    const int x = (tX << 3) + ((lane & 1) << 2);   // first of this lane's 4 x-voxels
    const int y = (tY << 3) + ((lane >> 1) & 7);
    const int z = (tZ << 2) + (lane >> 4);
    const float px = (x + 0.5f) * VOXF;
    const float py = (y + 0.5f) * VOXF;
    const float pz = (z + 0.5f) * VOXF;

    const float lox = ((tX << 3) + 0.5f) * VOXF, hix = ((tX << 3) + 7.5f) * VOXF;
    const float loy = ((tY << 3) + 0.5f) * VOXF, hiy = ((tY << 3) + 7.5f) * VOXF;
    const float loz = ((tZ << 2) + 0.5f) * VOXF, hiz = ((tZ << 2) + 3.5f) * VOXF;

    // ---- phase 1: cull this wave's 4 chunks into slist[wave] ----
    const int nch = (N + 63) >> 6;
    int off = 0;
    #pragma unroll
    for (int j = 0; j < 4; ++j) {
        const int c = q + (wave << 2) + (j << 4);
        if (c >= nch) break;
        const int gi = (c << 6) + lane;
        const int gc = gi < N ? gi : N - 1;
        float4 ca = ((const float4*)(ws + WS_CULLA))[gc];
        float4 cb = ((const float4*)(ws + WS_CULLB))[gc];
        bool keep = (gi < N)
            && (ca.x + ca.w >= lox) && (ca.x - ca.w <= hix)
            && (ca.y + cb.x >= loy) && (ca.y - cb.x <= hiy)
            && (ca.z + cb.y >= loz) && (ca.z - cb.y <= hiz);
        unsigned long long bal = __ballot(keep);
        int pre = __popcll(bal & ((1ull << lane) - 1ull));
        if (keep) slist[wave][off + pre] = gi;
        off += __popcll(bal);
    }
    if (lane == 0) lenw[wave] = off;
    __syncthreads();

    // ---- slice boundaries (uniform, deterministic) ----
    const int l0 = lenw[0], l1 = lenw[1], l2 = lenw[2], l3 = lenw[3];
    const int cum1 = l0, cum2 = l0 + l1, cum3 = cum2 + l2;
    const int cnt = cum3 + l3;
    const int beg = (wave * cnt) >> 2;
    const int end = ((wave + 1) * cnt) >> 2;

    float4 acc; acc.x = 0.f; acc.y = 0.f; acc.z = 0.f; acc.w = 0.f;

    // map concatenated position p -> gaussian index (all lanes uniform)
    #define FETCH_IDX(p) \
        slist[(p >= cum1) + (p >= cum2) + (p >= cum3)] \
             [p - ((p >= cum3) ? cum3 : (p >= cum2) ? cum2 : (p >= cum1) ? cum1 : 0)]

    // ---- phase 2: 2-deep s_load-pipelined survivor loop over [beg, end) ----
    if (beg < end) {
        int u0 = __builtin_amdgcn_readfirstlane(FETCH_IDX(beg));
        const float4* P = (const float4*)(rec + (size_t)u0 * 12);
        float4 a0 = P[0], a1 = P[1], a2 = P[2];

        bool hasB = (beg + 1 < end);
        float4 b0, b1, b2;
        if (hasB) {
            int u1 = __builtin_amdgcn_readfirstlane(FETCH_IDX(beg + 1));
            const float4* Q = (const float4*)(rec + (size_t)u1 * 12);
            b0 = Q[0]; b1 = Q[1]; b2 = Q[2];
        }

        int pc = beg + 2;
        while (true) {
            bool hasC = (pc < end);
            float4 e0, e1, e2;
            if (hasC) {
                int u2 = __builtin_amdgcn_readfirstlane(FETCH_IDX(pc));
                const float4* Q = (const float4*)(rec + (size_t)u2 * 12);
                e0 = Q[0]; e1 = Q[1]; e2 = Q[2];
                ++pc;
            }

            // all a* operands are SGPRs: <=1 SGPR per VALU instr holds
            float dy = py - a2.y, dz = pz - a2.z;
            float qyz = (a0.y * dy) * dy + (a0.z * dz + a1.y * dy) * dz;
            float gx  = a0.w * dy + a1.x * dz;
            float qmin = qyz - (gx * gx) * a1.z;   // scaled max of q' = min of q
            if (!__all(qmin < SKIPTH)) {           // some lane's strip reaches q < QCUT
                float dx0 = px - a2.x;
                float dx1 = dx0 + VOXF;
                float dx2 = dx0 + 2.0f * VOXF;
                float dx3 = dx0 + 3.0f * VOXF;
                float q0 = qyz + dx0 * (a0.x * dx0 + gx);
                float q1 = qyz + dx1 * (a0.x * dx1 + gx);
                float q2 = qyz + dx2 * (a0.x * dx2 + gx);
                float q3 = qyz + dx3 * (a0.x * dx3 + gx);
                float de = a1.w;
                acc.x += de * __builtin_amdgcn_exp2f(q0);
                acc.y += de * __builtin_amdgcn_exp2f(q1);
                acc.z += de * __builtin_amdgcn_exp2f(q2);
                acc.w += de * __builtin_amdgcn_exp2f(q3);
            }

            if (!hasB) break;
            a0 = b0; a1 = b1; a2 = b2;
            hasB = hasC;
            if (hasC) { b0 = e0; b1 = e1; b2 = e2; }
        }
    }
    #undef FETCH_IDX

    plds[wave][lane] = acc;
    __syncthreads();

    if (wave == 0) {
        float4 r = plds[0][lane];
        #pragma unroll
        for (int w = 1; w < 4; ++w) {       // fixed order: deterministic
            float4 p = plds[w][lane];
            r.x += p.x; r.y += p.y; r.z += p.z; r.w += p.w;
        }
        const int v = (z << 12) + (y << 6) + x;
        *(float4*)&part[(size_t)q * NVOX + v] = r;
    }
}

// out4[i] = sum over the 4 quarter-partials, fixed order -> deterministic
__global__ __launch_bounds__(256) void combine_kernel(
    const float* __restrict__ part, float* __restrict__ out)
{
    const int i = blockIdx.x * 256 + threadIdx.x;   // 65536 float4s
    const float4* p = (const float4*)part;
    float4 a = p[i];
    float4 b = p[i + (NVOX / 4)];
    float4 c = p[i + 2 * (NVOX / 4)];
    float4 d = p[i + 3 * (NVOX / 4)];
    float4 r;
    r.x = ((a.x + b.x) + c.x) + d.x;
    r.y = ((a.y + b.y) + c.y) + d.y;
    r.z = ((a.z + b.z) + c.z) + d.z;
    r.w = ((a.w + b.w) + c.w) + d.w;
    ((float4*)out)[i] = r;
}

extern "C" void kernel_launch(void* const* d_in, const int* in_sizes, int n_in,
                              void* d_out, int out_size, void* d_ws, size_t ws_size,
                              hipStream_t stream)
{
    const float* means  = (const float*)d_in[0];
    const float* dens   = (const float*)d_in[1];
    const float* scales = (const float*)d_in[2];
    const float* rots   = (const float*)d_in[3];
    float* out = (float*)d_out;
    float* ws  = (float*)d_ws;
    float* part = ws + WS_PART;
    const int N = in_sizes[1];

    prep_kernel<<<(N + 255) / 256, 256, 0, stream>>>(means, dens, scales, rots,
                                                     ws, out + NVOX, N);
    vox_kernel<<<4096, 256, 0, stream>>>(ws, part, N);
    combine_kernel<<<NVOX / 4 / 256, 256, 0, stream>>>(part, out);
}

// Round 10
// 31.632 us; speedup vs baseline: 1.5077x; 1.5077x over previous
//
#include <hip/hip_runtime.h>

#define GRIDN 64
#define NVOX (GRIDN * GRIDN * GRIDN)
#define VOXF (1.0f / 64.0f)
#define QCUT 16.0f               // contribution cut at e^-8 per (gaussian,voxel)
#define EXPSCL (-0.72134752044f) // -0.5 * log2(e)
#define SKIPTH (QCUT * EXPSCL)   // scaled-q threshold (includes folded log2-density)

// Workspace layout (float offsets), N=4096:
//  cullA[N] float4: (mux, muy, muz, rx)
//  cullB[N] float4: (ry, rz, sph_r2, 0)
//  rec[N]   4x float4 (64B stride, 3 used):
//     r0=(A',B',C',2D')  r1=(2E',2F', -0.25/A', log2(dens))  r2=(mu,0)
//  part[4*NVOX] quarter partial volumes
#define WS_CULLA 0
#define WS_CULLB (4 * 4096)
#define WS_REC   (8 * 4096)
#define WS_PART  (24 * 4096)

__global__ __launch_bounds__(256) void prep_kernel(
    const float* __restrict__ means, const float* __restrict__ dens,
    const float* __restrict__ scales, const float* __restrict__ rots,
    float* __restrict__ ws, float* __restrict__ radii_out, int N)
{
    int i = blockIdx.x * 256 + threadIdx.x;
    if (i >= N) return;

    float qw = rots[i * 4 + 0], qx = rots[i * 4 + 1];
    float qy = rots[i * 4 + 2], qz = rots[i * 4 + 3];
    float inm = rsqrtf(qw * qw + qx * qx + qy * qy + qz * qz);
    qw *= inm; qx *= inm; qy *= inm; qz *= inm;
    float r00 = 1.f - 2.f * (qy * qy + qz * qz);
    float r01 = 2.f * (qx * qy - qw * qz);
    float r02 = 2.f * (qx * qz + qw * qy);
    float r10 = 2.f * (qx * qy + qw * qz);
    float r11 = 1.f - 2.f * (qx * qx + qz * qz);
    float r12 = 2.f * (qy * qz - qw * qx);
    float r20 = 2.f * (qx * qz - qw * qy);
    float r21 = 2.f * (qy * qz + qw * qx);
    float r22 = 1.f - 2.f * (qx * qx + qy * qy);

    float s0 = scales[i * 3 + 0], s1 = scales[i * 3 + 1], s2 = scales[i * 3 + 2];
    float v0 = s0 * s0, v1 = s1 * s1, v2 = s2 * s2;
    float i0 = 1.f / v0, i1 = 1.f / v1, i2 = 1.f / v2;

    // Sinv = R diag(1/s^2) R^T, scaled by EXPSCL (negative)
    float A = (r00 * r00 * i0 + r01 * r01 * i1 + r02 * r02 * i2) * EXPSCL;
    float B = (r10 * r10 * i0 + r11 * r11 * i1 + r12 * r12 * i2) * EXPSCL;
    float C = (r20 * r20 * i0 + r21 * r21 * i1 + r22 * r22 * i2) * EXPSCL;
    float D = (r00 * r10 * i0 + r01 * r11 * i1 + r02 * r12 * i2) * EXPSCL;
    float E = (r00 * r20 * i0 + r01 * r21 * i1 + r02 * r22 * i2) * EXPSCL;
    float F = (r10 * r20 * i0 + r11 * r21 * i1 + r12 * r22 * i2) * EXPSCL;

    // Covariance diagonal -> per-axis extents of {q <= qeff}
    float Cxx = r00 * r00 * v0 + r01 * r01 * v1 + r02 * r02 * v2;
    float Cyy = r10 * r10 * v0 + r11 * r11 * v1 + r12 * r12 * v2;
    float Czz = r20 * r20 * v0 + r21 * r21 * v1 + r22 * r22 * v2;

    float de = fmaxf(dens[i], 1e-30f);
    // contribution-based cut: de*exp(-q/2) < e^-8  <=>  q > QCUT + 2 ln de
    float qeff = fmaxf(QCUT + 2.0f * logf(de), 0.0f);
    float smax2 = fmaxf(v0, fmaxf(v1, v2));

    float mx = means[i * 3 + 0], my = means[i * 3 + 1], mz = means[i * 3 + 2];
    float4 ca; ca.x = mx; ca.y = my; ca.z = mz; ca.w = sqrtf(qeff * Cxx);
    float4 cb; cb.x = sqrtf(qeff * Cyy); cb.y = sqrtf(qeff * Czz);
    cb.z = qeff * smax2; cb.w = 0.f;
    ((float4*)(ws + WS_CULLA))[i] = ca;
    ((float4*)(ws + WS_CULLB))[i] = cb;

    float4* R = (float4*)(ws + WS_REC + (size_t)i * 16);
    float4 w0; w0.x = A; w0.y = B; w0.z = C; w0.w = 2.f * D;
    float4 w1; w1.x = 2.f * E; w1.y = 2.f * F; w1.z = -0.25f / A; w1.w = log2f(de);
    float4 w2; w2.x = mx; w2.y = my; w2.z = mz; w2.w = 0.f;
    R[0] = w0; R[1] = w1; R[2] = w2;

    float m = fmaxf(s0, fmaxf(s1, s2));
    radii_out[i] = ceilf(m * 3.0f * 64.0f);
}

// scaled quadratic (A'<0), density folded into qyz via log2(dens):
// contribution = exp2(q'); strip-max test skips when all lanes < SKIPTH.
#define BODY(v0_, v1_, v2_) do {                                              \
    float dy = py - v2_.y, dz = pz - v2_.z;                                   \
    float tt  = fmaf(v1_.y, dy, v0_.z * dz);                                  \
    float qyz = fmaf(v0_.y * dy, dy, fmaf(tt, dz, v1_.w));                    \
    float gx  = fmaf(v0_.w, dy, v1_.x * dz);                                  \
    float qmx = fmaf(gx * gx, v1_.z, qyz);                                    \
    if (!__all(qmx < SKIPTH)) {                                               \
        float dx0 = px - v2_.x;                                               \
        float dx1 = dx0 + VOXF, dx2 = dx0 + 2.f * VOXF, dx3 = dx0 + 3.f * VOXF;\
        acc.x += __builtin_amdgcn_exp2f(fmaf(dx0, fmaf(v0_.x, dx0, gx), qyz));\
        acc.y += __builtin_amdgcn_exp2f(fmaf(dx1, fmaf(v0_.x, dx1, gx), qyz));\
        acc.z += __builtin_amdgcn_exp2f(fmaf(dx2, fmaf(v0_.x, dx2, gx), qyz));\
        acc.w += __builtin_amdgcn_exp2f(fmaf(dx3, fmaf(v0_.x, dx3, gx), qyz));\
    }                                                                         \
} while (0)

// 4096 blocks x 256 threads (4 waves). Tile = 8x8x4 voxels (VPT=4 along x);
// tile covered by 4 blocks (quarters of the gaussian chunks).
// Phase 1: waves cull their 4 chunks (AABB + sphere) into per-wave segments,
//          then flatten to one block-ordered list (stable -> deterministic).
// Phase 2: waves take equal slices; indices fetched 64-at-a-time into a VGPR
//          (one ds_read), per-iter index via v_readlane; records via uniform
//          s_load, manual unroll-2 (no rotation moves).
__global__ __launch_bounds__(256) void vox_kernel(
    const float* __restrict__ ws, float* __restrict__ part, int N)
{
    __shared__ int swseg[4][256];
    __shared__ int slist[1024];
    __shared__ int lenw[4];
    __shared__ float4 plds[4][64];

    const float* rec = ws + WS_REC;
    const int tid = threadIdx.x;
    const int lane = tid & 63, wave = tid >> 6;
    const int bs = (blockIdx.x * 1657) & 4095;   // bijective scramble
    const int tile = bs >> 2, q = bs & 3;
    const int tX = tile & 7, tY = (tile >> 3) & 7, tZ = tile >> 6;
    const int x = (tX << 3) + ((lane & 1) << 2);
    const int y = (tY << 3) + ((lane >> 1) & 7);
    const int z = (tZ << 2) + (lane >> 4);
    const float px = (x + 0.5f) * VOXF;
    const float py = (y + 0.5f) * VOXF;
    const float pz = (z + 0.5f) * VOXF;

    const float lox = ((tX << 3) + 0.5f) * VOXF, hix = ((tX << 3) + 7.5f) * VOXF;
    const float loy = ((tY << 3) + 0.5f) * VOXF, hiy = ((tY << 3) + 7.5f) * VOXF;
    const float loz = ((tZ << 2) + 0.5f) * VOXF, hiz = ((tZ << 2) + 3.5f) * VOXF;

    // ---- phase 1: cull 4 chunks into this wave's segment ----
    const int nch = (N + 63) >> 6;
    int off = 0;
    #pragma unroll
    for (int j = 0; j < 4; ++j) {
        const int c = q + (wave << 2) + (j << 4);
        if (c >= nch) break;
        const int gi = (c << 6) + lane;
        const int gc = gi < N ? gi : N - 1;
        float4 ca = ((const float4*)(ws + WS_CULLA))[gc];
        float4 cb = ((const float4*)(ws + WS_CULLB))[gc];
        // sphere: clamp-point distance vs qeff*smax^2
        float cx = fminf(fmaxf(ca.x, lox), hix) - ca.x;
        float cy = fminf(fmaxf(ca.y, loy), hiy) - ca.y;
        float cz = fminf(fmaxf(ca.z, loz), hiz) - ca.z;
        float d2 = fmaf(cx, cx, fmaf(cy, cy, cz * cz));
        bool keep = (gi < N) && (d2 <= cb.z)
            && (ca.x + ca.w >= lox) && (ca.x - ca.w <= hix)
            && (ca.y + cb.x >= loy) && (ca.y - cb.x <= hiy)
            && (ca.z + cb.y >= loz) && (ca.z - cb.y <= hiz);
        unsigned long long bal = __ballot(keep);
        int pre = __popcll(bal & ((1ull << lane) - 1ull));
        if (keep) swseg[wave][off + pre] = gi;
        off += __popcll(bal);
    }
    if (lane == 0) lenw[wave] = off;
    __syncthreads();

    // ---- flatten to block-ordered list ----
    const int l0 = lenw[0], l1 = lenw[1], l2 = lenw[2], l3 = lenw[3];
    const int cnt = l0 + l1 + l2 + l3;
    const int mybase = (wave > 0 ? l0 : 0) + (wave > 1 ? l1 : 0) + (wave > 2 ? l2 : 0);
    const int mylen = lenw[wave];
    for (int i = lane; i < mylen; i += 64) slist[mybase + i] = swseg[wave][i];
    __syncthreads();

    // ---- phase 2: equal slices, unroll-2 s_load pipeline ----
    const int beg = (wave * cnt) >> 2;
    const int end = ((wave + 1) * cnt) >> 2;

    float4 acc; acc.x = 0.f; acc.y = 0.f; acc.z = 0.f; acc.w = 0.f;

    for (int base = beg; base < end; base += 64) {
        int src = base + lane;
        int vidx = slist[src < cnt ? src : cnt - 1];  // one ds_read per 64 iters
        int navail = end - base; if (navail > 64) navail = 64;
        int j = 0;
        for (; j + 2 <= navail; j += 2) {
            int i0 = __builtin_amdgcn_readlane(vidx, j);
            int i1 = __builtin_amdgcn_readlane(vidx, j + 1);
            const float4* P = (const float4*)(rec + ((size_t)i0 << 4));
            const float4* Q = (const float4*)(rec + ((size_t)i1 << 4));
            float4 a0 = P[0], a1 = P[1], a2 = P[2];
            float4 b0 = Q[0], b1 = Q[1], b2 = Q[2];
            BODY(a0, a1, a2);
            BODY(b0, b1, b2);
        }
        if (j < navail) {
            int i0 = __builtin_amdgcn_readlane(vidx, j);
            const float4* P = (const float4*)(rec + ((size_t)i0 << 4));
            float4 a0 = P[0], a1 = P[1], a2 = P[2];
            BODY(a0, a1, a2);
        }
    }

    plds[wave][lane] = acc;
    __syncthreads();

    if (wave == 0) {
        float4 r = plds[0][lane];
        #pragma unroll
        for (int w = 1; w < 4; ++w) {        // fixed order: deterministic
            float4 p = plds[w][lane];
            r.x += p.x; r.y += p.y; r.z += p.z; r.w += p.w;
        }
        const int v = (z << 12) + (y << 6) + x;
        *(float4*)&part[(size_t)q * NVOX + v] = r;
    }
}

// out4[i] = sum of the 4 quarter-partials, fixed order -> deterministic
__global__ __launch_bounds__(256) void combine_kernel(
    const float* __restrict__ part, float* __restrict__ out)
{
    const int i = blockIdx.x * 256 + threadIdx.x;   // 65536 float4s
    const float4* p = (const float4*)part;
    float4 a = p[i];
    float4 b = p[i + (NVOX / 4)];
    float4 c = p[i + 2 * (NVOX / 4)];
    float4 d = p[i + 3 * (NVOX / 4)];
    float4 r;
    r.x = ((a.x + b.x) + c.x) + d.x;
    r.y = ((a.y + b.y) + c.y) + d.y;
    r.z = ((a.z + b.z) + c.z) + d.z;
    r.w = ((a.w + b.w) + c.w) + d.w;
    ((float4*)out)[i] = r;
}

extern "C" void kernel_launch(void* const* d_in, const int* in_sizes, int n_in,
                              void* d_out, int out_size, void* d_ws, size_t ws_size,
                              hipStream_t stream)
{
    const float* means  = (const float*)d_in[0];
    const float* dens   = (const float*)d_in[1];
    const float* scales = (const float*)d_in[2];
    const float* rots   = (const float*)d_in[3];
    float* out = (float*)d_out;
    float* ws  = (float*)d_ws;
    float* part = ws + WS_PART;
    const int N = in_sizes[1];

    prep_kernel<<<(N + 255) / 256, 256, 0, stream>>>(means, dens, scales, rots,
                                                     ws, out + NVOX, N);
    vox_kernel<<<4096, 256, 0, stream>>>(ws, part, N);
    combine_kernel<<<NVOX / 4 / 256, 256, 0, stream>>>(part, out);
}

// Round 11
// 31.595 us; speedup vs baseline: 1.5094x; 1.0012x over previous
//
#include <hip/hip_runtime.h>

#define GRIDN 64
#define NVOX (GRIDN * GRIDN * GRIDN)
#define VOXF (1.0f / 64.0f)
#define QCUT 16.0f               // contribution cut at e^-8 per (gaussian,voxel)
#define EXPSCL (-0.72134752044f) // -0.5 * log2(e)
#define SKIPTH (QCUT * EXPSCL)   // scaled-q threshold (includes folded log2-density)

// Workspace layout (float offsets), N=4096:
//  cullA[N] float4: (mux, muy, muz, rx)
//  cullB[N] float4: (ry, rz, sph_r2, 0)
//  rec[N]   4x float4 (64B stride, 3 used):
//     r0=(A',B',C',2D')  r1=(2E',2F', -0.25/A', log2(dens))  r2=(mu,0)
//  part[4*NVOX] quarter partial volumes
#define WS_CULLA 0
#define WS_CULLB (4 * 4096)
#define WS_REC   (8 * 4096)
#define WS_PART  (24 * 4096)

__global__ __launch_bounds__(256) void prep_kernel(
    const float* __restrict__ means, const float* __restrict__ dens,
    const float* __restrict__ scales, const float* __restrict__ rots,
    float* __restrict__ ws, float* __restrict__ radii_out, int N)
{
    int i = blockIdx.x * 256 + threadIdx.x;
    if (i >= N) return;

    float qw = rots[i * 4 + 0], qx = rots[i * 4 + 1];
    float qy = rots[i * 4 + 2], qz = rots[i * 4 + 3];
    float inm = rsqrtf(qw * qw + qx * qx + qy * qy + qz * qz);
    qw *= inm; qx *= inm; qy *= inm; qz *= inm;
    float r00 = 1.f - 2.f * (qy * qy + qz * qz);
    float r01 = 2.f * (qx * qy - qw * qz);
    float r02 = 2.f * (qx * qz + qw * qy);
    float r10 = 2.f * (qx * qy + qw * qz);
    float r11 = 1.f - 2.f * (qx * qx + qz * qz);
    float r12 = 2.f * (qy * qz - qw * qx);
    float r20 = 2.f * (qx * qz - qw * qy);
    float r21 = 2.f * (qy * qz + qw * qx);
    float r22 = 1.f - 2.f * (qx * qx + qy * qy);

    float s0 = scales[i * 3 + 0], s1 = scales[i * 3 + 1], s2 = scales[i * 3 + 2];
    float v0 = s0 * s0, v1 = s1 * s1, v2 = s2 * s2;
    float i0 = 1.f / v0, i1 = 1.f / v1, i2 = 1.f / v2;

    // Sinv = R diag(1/s^2) R^T, scaled by EXPSCL (negative)
    float A = (r00 * r00 * i0 + r01 * r01 * i1 + r02 * r02 * i2) * EXPSCL;
    float B = (r10 * r10 * i0 + r11 * r11 * i1 + r12 * r12 * i2) * EXPSCL;
    float C = (r20 * r20 * i0 + r21 * r21 * i1 + r22 * r22 * i2) * EXPSCL;
    float D = (r00 * r10 * i0 + r01 * r11 * i1 + r02 * r12 * i2) * EXPSCL;
    float E = (r00 * r20 * i0 + r01 * r21 * i1 + r02 * r22 * i2) * EXPSCL;
    float F = (r10 * r20 * i0 + r11 * r21 * i1 + r12 * r22 * i2) * EXPSCL;

    // Covariance diagonal -> per-axis extents of {q <= qeff}
    float Cxx = r00 * r00 * v0 + r01 * r01 * v1 + r02 * r02 * v2;
    float Cyy = r10 * r10 * v0 + r11 * r11 * v1 + r12 * r12 * v2;
    float Czz = r20 * r20 * v0 + r21 * r21 * v1 + r22 * r22 * v2;

    float de = fmaxf(dens[i], 1e-30f);
    // contribution-based cut: de*exp(-q/2) < e^-8  <=>  q > QCUT + 2 ln de
    float qeff = fmaxf(QCUT + 2.0f * logf(de), 0.0f);
    float smax2 = fmaxf(v0, fmaxf(v1, v2));

    float mx = means[i * 3 + 0], my = means[i * 3 + 1], mz = means[i * 3 + 2];
    float4 ca; ca.x = mx; ca.y = my; ca.z = mz; ca.w = sqrtf(qeff * Cxx);
    float4 cb; cb.x = sqrtf(qeff * Cyy); cb.y = sqrtf(qeff * Czz);
    cb.z = qeff * smax2; cb.w = 0.f;
    ((float4*)(ws + WS_CULLA))[i] = ca;
    ((float4*)(ws + WS_CULLB))[i] = cb;

    float4* R = (float4*)(ws + WS_REC + (size_t)i * 16);
    float4 w0; w0.x = A; w0.y = B; w0.z = C; w0.w = 2.f * D;
    float4 w1; w1.x = 2.f * E; w1.y = 2.f * F; w1.z = -0.25f / A; w1.w = log2f(de);
    float4 w2; w2.x = mx; w2.y = my; w2.z = mz; w2.w = 0.f;
    R[0] = w0; R[1] = w1; R[2] = w2;

    float m = fmaxf(s0, fmaxf(s1, s2));
    radii_out[i] = ceilf(m * 3.0f * 64.0f);
}

// scaled quadratic (A'<0), density folded into qyz via log2(dens):
// contribution = exp2(q'); strip-max test skips when all lanes < SKIPTH.
#define BODY(v0_, v1_, v2_) do {                                              \
    float dy = py - v2_.y, dz = pz - v2_.z;                                   \
    float tt  = fmaf(v1_.y, dy, v0_.z * dz);                                  \
    float qyz = fmaf(v0_.y * dy, dy, fmaf(tt, dz, v1_.w));                    \
    float gx  = fmaf(v0_.w, dy, v1_.x * dz);                                  \
    float qmx = fmaf(gx * gx, v1_.z, qyz);                                    \
    if (!__all(qmx < SKIPTH)) {                                               \
        float dx0 = px - v2_.x;                                               \
        float dx1 = dx0 + VOXF, dx2 = dx0 + 2.f * VOXF, dx3 = dx0 + 3.f * VOXF;\
        acc.x += __builtin_amdgcn_exp2f(fmaf(dx0, fmaf(v0_.x, dx0, gx), qyz));\
        acc.y += __builtin_amdgcn_exp2f(fmaf(dx1, fmaf(v0_.x, dx1, gx), qyz));\
        acc.z += __builtin_amdgcn_exp2f(fmaf(dx2, fmaf(v0_.x, dx2, gx), qyz));\
        acc.w += __builtin_amdgcn_exp2f(fmaf(dx3, fmaf(v0_.x, dx3, gx), qyz));\
    }                                                                         \
} while (0)

// 4096 blocks x 256 threads (4 waves). Tile = 8x8x4 voxels (VPT=4 along x);
// tile covered by 4 blocks (quarters of the gaussian chunks).
// Phase 1: waves cull their 4 chunks (AABB + sphere) into per-wave segments,
//          then flatten to one block-ordered list (stable -> deterministic).
// Phase 2: waves take equal slices; indices fetched 64-at-a-time into a VGPR
//          (one ds_read), per-iter index via v_readlane; records via uniform
//          s_load, manual unroll-2 (no rotation moves).
__global__ __launch_bounds__(256) void vox_kernel(
    const float* __restrict__ ws, float* __restrict__ part, int N)
{
    __shared__ int swseg[4][256];
    __shared__ int slist[1024];
    __shared__ int lenw[4];
    __shared__ float4 plds[4][64];

    const float* rec = ws + WS_REC;
    const int tid = threadIdx.x;
    const int lane = tid & 63, wave = tid >> 6;
    const int bs = (blockIdx.x * 1657) & 4095;   // bijective scramble
    const int tile = bs >> 2, q = bs & 3;
    const int tX = tile & 7, tY = (tile >> 3) & 7, tZ = tile >> 6;
    const int x = (tX << 3) + ((lane & 1) << 2);
    const int y = (tY << 3) + ((lane >> 1) & 7);
    const int z = (tZ << 2) + (lane >> 4);
    const float px = (x + 0.5f) * VOXF;
    const float py = (y + 0.5f) * VOXF;
    const float pz = (z + 0.5f) * VOXF;

    const float lox = ((tX << 3) + 0.5f) * VOXF, hix = ((tX << 3) + 7.5f) * VOXF;
    const float loy = ((tY << 3) + 0.5f) * VOXF, hiy = ((tY << 3) + 7.5f) * VOXF;
    const float loz = ((tZ << 2) + 0.5f) * VOXF, hiz = ((tZ << 2) + 3.5f) * VOXF;

    // ---- phase 1: cull 4 chunks into this wave's segment ----
    const int nch = (N + 63) >> 6;
    int off = 0;
    #pragma unroll
    for (int j = 0; j < 4; ++j) {
        const int c = q + (wave << 2) + (j << 4);
        if (c >= nch) break;
        const int gi = (c << 6) + lane;
        const int gc = gi < N ? gi : N - 1;
        float4 ca = ((const float4*)(ws + WS_CULLA))[gc];
        float4 cb = ((const float4*)(ws + WS_CULLB))[gc];
        // sphere: clamp-point distance vs qeff*smax^2
        float cx = fminf(fmaxf(ca.x, lox), hix) - ca.x;
        float cy = fminf(fmaxf(ca.y, loy), hiy) - ca.y;
        float cz = fminf(fmaxf(ca.z, loz), hiz) - ca.z;
        float d2 = fmaf(cx, cx, fmaf(cy, cy, cz * cz));
        bool keep = (gi < N) && (d2 <= cb.z)
            && (ca.x + ca.w >= lox) && (ca.x - ca.w <= hix)
            && (ca.y + cb.x >= loy) && (ca.y - cb.x <= hiy)
            && (ca.z + cb.y >= loz) && (ca.z - cb.y <= hiz);
        unsigned long long bal = __ballot(keep);
        int pre = __popcll(bal & ((1ull << lane) - 1ull));
        if (keep) swseg[wave][off + pre] = gi;
        off += __popcll(bal);
    }
    if (lane == 0) lenw[wave] = off;
    __syncthreads();

    // ---- flatten to block-ordered list ----
    const int l0 = lenw[0], l1 = lenw[1], l2 = lenw[2], l3 = lenw[3];
    const int cnt = l0 + l1 + l2 + l3;
    const int mybase = (wave > 0 ? l0 : 0) + (wave > 1 ? l1 : 0) + (wave > 2 ? l2 : 0);
    const int mylen = lenw[wave];
    for (int i = lane; i < mylen; i += 64) slist[mybase + i] = swseg[wave][i];
    __syncthreads();

    // ---- phase 2: equal slices, unroll-2 s_load pipeline ----
    const int beg = (wave * cnt) >> 2;
    const int end = ((wave + 1) * cnt) >> 2;

    float4 acc; acc.x = 0.f; acc.y = 0.f; acc.z = 0.f; acc.w = 0.f;

    for (int base = beg; base < end; base += 64) {
        int src = base + lane;
        int vidx = slist[src < cnt ? src : cnt - 1];  // one ds_read per 64 iters
        int navail = end - base; if (navail > 64) navail = 64;
        int j = 0;
        for (; j + 2 <= navail; j += 2) {
            int i0 = __builtin_amdgcn_readlane(vidx, j);
            int i1 = __builtin_amdgcn_readlane(vidx, j + 1);
            const float4* P = (const float4*)(rec + ((size_t)i0 << 4));
            const float4* Q = (const float4*)(rec + ((size_t)i1 << 4));
            float4 a0 = P[0], a1 = P[1], a2 = P[2];
            float4 b0 = Q[0], b1 = Q[1], b2 = Q[2];
            BODY(a0, a1, a2);
            BODY(b0, b1, b2);
        }
        if (j < navail) {
            int i0 = __builtin_amdgcn_readlane(vidx, j);
            const float4* P = (const float4*)(rec + ((size_t)i0 << 4));
            float4 a0 = P[0], a1 = P[1], a2 = P[2];
            BODY(a0, a1, a2);
        }
    }

    plds[wave][lane] = acc;
    __syncthreads();

    if (wave == 0) {
        float4 r = plds[0][lane];
        #pragma unroll
        for (int w = 1; w < 4; ++w) {        // fixed order: deterministic
            float4 p = plds[w][lane];
            r.x += p.x; r.y += p.y; r.z += p.z; r.w += p.w;
        }
        const int v = (z << 12) + (y << 6) + x;
        *(float4*)&part[(size_t)q * NVOX + v] = r;
    }
}

// out4[i] = sum of the 4 quarter-partials, fixed order -> deterministic
__global__ __launch_bounds__(256) void combine_kernel(
    const float* __restrict__ part, float* __restrict__ out)
{
    const int i = blockIdx.x * 256 + threadIdx.x;   // 65536 float4s
    const float4* p = (const float4*)part;
    float4 a = p[i];
    float4 b = p[i + (NVOX / 4)];
    float4 c = p[i + 2 * (NVOX / 4)];
    float4 d = p[i + 3 * (NVOX / 4)];
    float4 r;
    r.x = ((a.x + b.x) + c.x) + d.x;
    r.y = ((a.y + b.y) + c.y) + d.y;
    r.z = ((a.z + b.z) + c.z) + d.z;
    r.w = ((a.w + b.w) + c.w) + d.w;
    ((float4*)out)[i] = r;
}

extern "C" void kernel_launch(void* const* d_in, const int* in_sizes, int n_in,
                              void* d_out, int out_size, void* d_ws, size_t ws_size,
                              hipStream_t stream)
{
    const float* means  = (const float*)d_in[0];
    const float* dens   = (const float*)d_in[1];
    const float* scales = (const float*)d_in[2];
    const float* rots   = (const float*)d_in[3];
    float* out = (float*)d_out;
    float* ws  = (float*)d_ws;
    float* part = ws + WS_PART;
    const int N = in_sizes[1];

    prep_kernel<<<(N + 255) / 256, 256, 0, stream>>>(means, dens, scales, rots,
                                                     ws, out + NVOX, N);
    vox_kernel<<<4096, 256, 0, stream>>>(ws, part, N);
    combine_kernel<<<NVOX / 4 / 256, 256, 0, stream>>>(part, out);
}